// Round 8
// baseline (159.857 us; speedup 1.0000x reference)
//
#include <hip/hip_runtime.h>
#include <hip/hip_fp16.h>

typedef _Float16 h2 __attribute__((ext_vector_type(2)));

#define BB 4
#define CIN 64
#define COUT 64
#define NN 40960
#define KK 16
#define GBLK (BB * NN / 256)   // 640 k_gemm blocks
#define FPAD 264
#define WPAD 68
#define HP 32                  // idx shares per batch
#define HWORDS (NN / 4)        // 10240 u32 words (4 u8 bins per word)
#define TP 37                  // k_final tile pitch: 2-way banks on read & write

// Privatized histogram, u8-packed, single range: block (b,p) bins its idx
// share into 40KB LDS, plain stores. No global atomics, idx read once.
// Overflow-safe: share=20480 uniform over 40960 bins -> max bin ~8 << 255.
__global__ __launch_bounds__(256) void k_hist(const int* __restrict__ idx,
                                              unsigned int* __restrict__ hist) {
    __shared__ unsigned int bins[HWORDS];   // 40 KB
    const int tid = threadIdx.x;
    const int b = blockIdx.x >> 5;          // HP = 32
    const int p = blockIdx.x & (HP - 1);

#pragma unroll
    for (int i = 0; i < HWORDS / 256; ++i) bins[i * 256 + tid] = 0u;
    __syncthreads();

    const int SHARE = NN * KK / HP;         // 20480
    const int4* src = (const int4*)(idx + (size_t)b * NN * KK + (size_t)p * SHARE);
#pragma unroll 4
    for (int i = 0; i < SHARE / 4 / 256; ++i) { // 20 iters
        int4 v = src[i * 256 + tid];
        atomicAdd(&bins[(unsigned)v.x >> 2], 1u << (((unsigned)v.x & 3) * 8));
        atomicAdd(&bins[(unsigned)v.y >> 2], 1u << (((unsigned)v.y & 3) * 8));
        atomicAdd(&bins[(unsigned)v.z >> 2], 1u << (((unsigned)v.z & 3) * 8));
        atomicAdd(&bins[(unsigned)v.w >> 2], 1u << (((unsigned)v.w & 3) * 8));
    }
    __syncthreads();
    unsigned int* dst = hist + (size_t)blockIdx.x * HWORDS;
#pragma unroll
    for (int i = 0; i < HWORDS / 256; ++i) dst[i * 256 + tid] = bins[i * 256 + tid];
}

// g split into half-rows: g_lo[n][ch0..31], g_hi[n][ch32..63] (64B rows)
// so each (batch,half) gather partition is 2.6MB -> L2-resident per XCD.
__global__ __launch_bounds__(256) void k_gemm(const float* __restrict__ feat,
                                              const float* __restrict__ W,
                                              const unsigned char* __restrict__ hist,
                                              __half* __restrict__ g_lo,
                                              __half* __restrict__ g_hi,
                                              float* __restrict__ partials) {
    __shared__ float Wt_s[64 * WPAD];
    __shared__ float feat_s[16 * FPAD];  // reused as red[2][64][33] in epilogue
    __shared__ float w_s[256];

    const int tid = threadIdx.x;
    const int b   = blockIdx.x / (NN / 256);
    const int n0  = (blockIdx.x % (NN / 256)) * 256;

    // merge u8 private histograms for this block's 256 bins (coalesced bytes)
    {
        const int n = n0 + tid;
        unsigned s = 1u;                     // +1 self reference
#pragma unroll
        for (int p = 0; p < HP; ++p)
            s += hist[(size_t)(b * HP + p) * NN + n];
        w_s[tid] = (float)s;
    }

    // stage W transposed (coalesced read, once)
#pragma unroll
    for (int it = 0; it < 16; ++it) {
        int c = tid & 63;
        int o = it * 4 + (tid >> 6);
        Wt_s[c * WPAD + o] = W[o * 64 + c];
    }

    const int to = tid & 7;
    const int tn = tid >> 3;

    float acc[8][8];
#pragma unroll
    for (int i = 0; i < 8; ++i)
#pragma unroll
        for (int j = 0; j < 8; ++j) acc[i][j] = 0.f;

    const float* fb = feat + (size_t)b * CIN * NN + n0;

    for (int cc0 = 0; cc0 < 64; cc0 += 16) {
        __syncthreads();
        {
            int row = tid >> 4;
            int col = (tid & 15) * 4;
            const float* src = fb + (size_t)(cc0 + row) * NN + col;
#pragma unroll
            for (int q = 0; q < 4; ++q) {
                float4 v = *(const float4*)(src + q * 64);
                *(float4*)&feat_s[row * FPAD + col + q * 64] = v;
            }
        }
        __syncthreads();

#pragma unroll
        for (int cc = 0; cc < 16; ++cc) {
            int c = cc0 + cc;
            float4 w0 = *(const float4*)&Wt_s[c * WPAD + to * 8];
            float4 w1 = *(const float4*)&Wt_s[c * WPAD + to * 8 + 4];
            float4 f0 = *(const float4*)&feat_s[cc * FPAD + tn * 8];
            float4 f1 = *(const float4*)&feat_s[cc * FPAD + tn * 8 + 4];
            float wv[8] = {w0.x, w0.y, w0.z, w0.w, w1.x, w1.y, w1.z, w1.w};
            float fv[8] = {f0.x, f0.y, f0.z, f0.w, f1.x, f1.y, f1.z, f1.w};
#pragma unroll
            for (int i = 0; i < 8; ++i)
#pragma unroll
                for (int j = 0; j < 8; ++j)
                    acc[i][j] = fmaf(wv[i], fv[j], acc[i][j]);
        }
    }

    // store g fp16, split: to<4 -> lo half (ch to*8), to>=4 -> hi half
    __half* glo_b = g_lo + ((size_t)b * NN + n0) * 32;
    __half* ghi_b = g_hi + ((size_t)b * NN + n0) * 32;
#pragma unroll
    for (int j = 0; j < 8; ++j) {
        int n = tn * 8 + j;
        union { uint4 u; h2 h[4]; } P;
#pragma unroll
        for (int h = 0; h < 4; ++h) {
            h2 t;
            t.x = (_Float16)acc[2 * h][j];
            t.y = (_Float16)acc[2 * h + 1][j];
            P.h[h] = t;
        }
        __half* dst = (to < 4) ? (glo_b + (size_t)n * 32 + to * 8)
                               : (ghi_b + (size_t)n * 32 + (to - 4) * 8);
        *(uint4*)dst = P.u;
    }

    // fused weighted stats (fp32 accumulators, pre-rounding)
    float wgt[8];
#pragma unroll
    for (int j = 0; j < 8; ++j) wgt[j] = w_s[tn * 8 + j];
    float s1[8], s2[8];
#pragma unroll
    for (int i = 0; i < 8; ++i) { s1[i] = 0.f; s2[i] = 0.f; }
#pragma unroll
    for (int j = 0; j < 8; ++j)
#pragma unroll
        for (int i = 0; i < 8; ++i) {
            float wv = wgt[j] * acc[i][j];
            s1[i] += wv;
            s2[i] += wv * acc[i][j];
        }

    __syncthreads();
    float* red = feat_s;  // [2][64][33]
#pragma unroll
    for (int i = 0; i < 8; ++i) {
        int o = to * 8 + i;
        red[o * 33 + tn]        = s1[i];
        red[2112 + o * 33 + tn] = s2[i];
    }
    __syncthreads();
    if (tid < 128) {
        int arr = tid >> 6, o = tid & 63;
        const float* base = red + arr * 2112 + o * 33;
        float s = 0.f;
#pragma unroll
        for (int t = 0; t < 32; ++t) s += base[t];
        partials[blockIdx.x * 128 + arr * 64 + o] = s;
    }
}

__global__ __launch_bounds__(1024) void k_finalize(const float* __restrict__ partials,
                                                   const float* __restrict__ gamma,
                                                   const float* __restrict__ beta,
                                                   _Float16* __restrict__ params_h) {
    const int i = threadIdx.x & 127;
    const int r = threadIdx.x >> 7;
    double a0 = 0, a1 = 0, a2 = 0, a3 = 0;
    for (int base = r; base < GBLK; base += 32) {
        a0 += (double)partials[(base)      * 128 + i];
        a1 += (double)partials[(base + 8)  * 128 + i];
        a2 += (double)partials[(base + 16) * 128 + i];
        a3 += (double)partials[(base + 24) * 128 + i];
    }
    __shared__ double red[8][128];
    red[r][i] = (a0 + a1) + (a2 + a3);
    __syncthreads();
    if (threadIdx.x < 64) {
        const int o = threadIdx.x;
        double s1 = 0.0, s2 = 0.0;
#pragma unroll
        for (int rr = 0; rr < 8; ++rr) { s1 += red[rr][o]; s2 += red[rr][64 + o]; }
        const double TOT = (double)BB * NN * (KK + 1);
        double mean = s1 / TOT;
        double var  = s2 / TOT - mean * mean;
        double inv  = 1.0 / sqrt(var + 1e-6);
        float scale = (float)inv * gamma[o];
        float shift = beta[o] - (float)mean * scale;
        params_h[o]      = (_Float16)scale;
        params_h[64 + o] = (_Float16)shift;
    }
}

// out[b][o][n] = sum over {n, idx[b,n,:]} of leakyrelu(g*scale+shift)
// Partition (batch, half) -> XCD via blockIdx%8: each XCD gathers from a
// 2.6MB g-half slice (L2-resident). 4 lanes/point x dwordx4 = one 64B row.
// GRID = 8 * (NN/256) = 1280 (p encodes batch AND half; chunk in [0,160)).
__global__ __launch_bounds__(256) void k_final(const __half* __restrict__ g_lo,
                                               const __half* __restrict__ g_hi,
                                               const int* __restrict__ idx,
                                               const _Float16* __restrict__ params_h,
                                               float* __restrict__ out) {
    const int tid  = threadIdx.x;
    const int lane = tid & 63;
    const int wave = tid >> 6;
    const int p     = blockIdx.x & 7;       // XCD partition = (b, half)
    const int chunk = blockIdx.x >> 3;      // 0..159
    const int b     = p >> 1;
    const int h     = p & 1;
    const int n0    = chunk * 256;

    __shared__ int   idx_s[256 * 17];       // 17.4 KB, pitch 17
    __shared__ float tile[256 * TP];        // 37.9 KB, pitch 37 (2-way banks)

    // stage idx: 4096 ints = 1024 int4, 4 per thread, coalesced
    {
        const int4* src = (const int4*)(idx + ((size_t)b * NN + n0) * KK);
#pragma unroll
        for (int i = 0; i < 4; ++i) {
            int e = i * 256 + tid;
            int4 v = src[e];
            int pt = e >> 2, k4 = (e & 3) * 4;
            idx_s[pt * 17 + k4 + 0] = v.x;
            idx_s[pt * 17 + k4 + 1] = v.y;
            idx_s[pt * 17 + k4 + 2] = v.z;
            idx_s[pt * 17 + k4 + 3] = v.w;
        }
    }

    const int q = (lane & 3) * 8;           // channel octet within half
    h2 sc2[4], sh2[4];
#pragma unroll
    for (int hh = 0; hh < 4; ++hh) {
        h2 a, s;
        a.x = params_h[h * 32 + q + 2 * hh];      a.y = params_h[h * 32 + q + 2 * hh + 1];
        s.x = params_h[64 + h * 32 + q + 2 * hh]; s.y = params_h[64 + h * 32 + q + 2 * hh + 1];
        sc2[hh] = a; sh2[hh] = s;
    }
    __syncthreads();

    const __half* gb = (h ? g_hi : g_lo) + (size_t)b * NN * 32;

#pragma unroll
    for (int it = 0; it < 4; ++it) {
        const int pt = wave * 64 + it * 16 + (lane >> 2);
        h2 acc[4];
#pragma unroll
        for (int hh = 0; hh < 4; ++hh) acc[hh] = (h2)(_Float16)0;

#pragma unroll
        for (int k = -1; k < KK; ++k) {
            int m = (k < 0) ? (n0 + pt) : idx_s[pt * 17 + k];
            union { uint4 u; h2 h[4]; } U;
            U.u = *(const uint4*)(gb + (size_t)m * 32 + q);
#pragma unroll
            for (int hh = 0; hh < 4; ++hh) {
                h2 t = U.h[hh] * sc2[hh] + sh2[hh];
                acc[hh] += __builtin_elementwise_max(t, t * (_Float16)0.2f);
            }
        }
        float* tr = &tile[pt * TP + q];
#pragma unroll
        for (int hh = 0; hh < 4; ++hh) {
            tr[2 * hh]     = (float)acc[hh].x;
            tr[2 * hh + 1] = (float)acc[hh].y;
        }
    }
    __syncthreads();

    // transpose-store: 32 o-rows x 256 n, coalesced 128B segments
    const int oo   = tid >> 3;              // 0..31
    const int nsub = tid & 7;
    float* ob = out + ((size_t)(b * 64 + h * 32 + oo)) * NN + n0;
#pragma unroll
    for (int pass = 0; pass < 8; ++pass) {
        int nl = pass * 32 + nsub * 4;
        float4 v = make_float4(tile[(nl + 0) * TP + oo], tile[(nl + 1) * TP + oo],
                               tile[(nl + 2) * TP + oo], tile[(nl + 3) * TP + oo]);
        *(float4*)&ob[nl] = v;
    }
}

extern "C" void kernel_launch(void* const* d_in, const int* in_sizes, int n_in,
                              void* d_out, int out_size, void* d_ws, size_t ws_size,
                              hipStream_t stream) {
    const float* feat  = (const float*)d_in[0];
    const float* W     = (const float*)d_in[1];
    const float* gamma = (const float*)d_in[2];
    const float* beta  = (const float*)d_in[3];
    const int*   idx   = (const int*)d_in[4];
    float* out = (float*)d_out;

    char* ws = (char*)d_ws;
    __half* g_lo = (__half*)ws;
    size_t off = (size_t)BB * NN * 32 * sizeof(__half);               // 10,485,760
    __half* g_hi = (__half*)(ws + off);
    off += (size_t)BB * NN * 32 * sizeof(__half);                     // +10,485,760
    unsigned char* hist = (unsigned char*)(ws + off);
    off += (size_t)BB * HP * NN;                                      // +5,242,880
    float* partials = (float*)(ws + off);
    off += (size_t)GBLK * 128 * sizeof(float);                        // +327,680
    _Float16* params_h = (_Float16*)(ws + off);

    k_hist<<<BB * HP, 256, 0, stream>>>(idx, (unsigned int*)hist);
    k_gemm<<<GBLK, 256, 0, stream>>>(feat, W, hist, g_lo, g_hi, partials);
    k_finalize<<<1, 1024, 0, stream>>>(partials, gamma, beta, params_h);
    k_final<<<8 * (NN / 256), 256, 0, stream>>>(g_lo, g_hi, idx, params_h, out);
}